// Round 5
// baseline (2652.506 us; speedup 1.0000x reference)
//
#include <hip/hip_runtime.h>

#define WAY   100
#define SHOT  5
#define NQ    15
#define DD    4096
#define N_L   500
#define N_U   1500
#define N_TOT 2000
#define LAMF  10.0f
#define EPSF  1e-6f
#define MAXIT 1000

// ---- workspace layout (float offsets) ----
#define OFF_Z      0u          // Z fp32 2000*4096 = 8192000; labeled half (rows 0..499) dead after
                               //   musinit -> Zb (bf16 Zu, 1536*4096 shorts = 1572864 fl) overlays it
#define OFF_MEANL  8388608u    // 4096 col sums; binit(100) after k_center
#define OFF_MEANU  8392704u    // 4096
#define OFF_SL     8396800u    // 100*4096
#define OFF_MUSA   8806400u    // 112*4096
#define OFF_MUSB   9265152u    // 112*4096
#define OFF_MUSQ   9723904u    // 128
#define OFF_MUSB16 9724032u    // bf16 mus 112*4096 sh = 229376 fl
#define OFF_PT     9953408u    // bf16 P^T 112*1536 sh = 86016 fl
#define OFF_KMAT   10039424u   // 150000
#define OFF_PMAT   10189424u   // 150000
#define OFF_COLS   10339424u   // 3*100*32 = 9600
#define OFF_MISC   10349024u   // [0..2]=err3(u), [3]=Ksum(f), [4]=cnt(u), [5]=gen(u), [6]=ctr(u)
#define OFF_ZUT    10349056u   // bf16 Zu^T 4096*1536 sh = 1572864 fl
#define OFF_D2P    11921920u   // max(D2PT 4*172032=688128, CP 112*4096=458752) -> ends 12610048 fl

#define G1_SPLIT 4
#define G1_KLEN  1024          // 4096/4
#define D2P_STRIDE 172032u     // 112*1536
#define SINK_BLOCKS 8
#define RPB 188                // rows per sinkhorn block (8*188 = 1504 >= 1500)
#define KLP 101                // padded Kl row stride: bank stride 5, conflict-free
#define PTS 1536               // P^T / ZuT row stride (shorts)

typedef __attribute__((ext_vector_type(8))) short short8_t;
typedef __attribute__((ext_vector_type(4))) float f32x4;

// fp32 -> bf16 bits, round-to-nearest-even (normal values)
__device__ __forceinline__ short f2bs(float f) {
  unsigned u = __float_as_uint(f);
  unsigned r = (u + 0x7FFFu + ((u >> 16) & 1u)) >> 16;
  return (short)r;
}

// ---------------- preprocessing ----------------
__global__ __launch_bounds__(256) void k_pow_norm(const float* __restrict__ X, float* __restrict__ Z,
                                                  float* __restrict__ msums, unsigned* __restrict__ misc_u) {
  int i = blockIdx.x, tid = threadIdx.x;
  __shared__ float red[256];
  if (i < 32) msums[i * 256 + tid] = 0.f;
  if (i == 32 && tid < 16) misc_u[tid] = 0u;
  const float* x = X + (size_t)i * DD;
  float s = 0.f;
  for (int k = tid; k < DD; k += 256) s += x[k] + 1e-6f;
  red[tid] = s; __syncthreads();
  for (int o = 128; o > 0; o >>= 1) { if (tid < o) red[tid] += red[tid + o]; __syncthreads(); }
  float inv = 1.0f / fmaxf(sqrtf(red[0]), 1e-12f);
  float* z = Z + (size_t)i * DD;
  for (int k = tid; k < DD; k += 256) z[k] = sqrtf(x[k] + 1e-6f) * inv;
}

__global__ __launch_bounds__(256) void k_colmeans(const float* __restrict__ Z, float* __restrict__ mLs,
                                                  float* __restrict__ mUs) {
  int k = blockIdx.x * 256 + threadIdx.x;
  int r0 = blockIdx.y * 80;
  float sL = 0.f, sU = 0.f;
  for (int r = r0; r < r0 + 80; ++r) {
    float v = Z[(size_t)r * DD + k];
    if (r < N_L) sL += v; else sU += v;
  }
  if (r0 < N_L) atomicAdd(&mLs[k], sL);
  if (r0 + 80 > N_L) atomicAdd(&mUs[k], sU);
}

__global__ __launch_bounds__(256) void k_center(float* __restrict__ Z, const float* __restrict__ mLs,
                                                const float* __restrict__ mUs) {
  int i = blockIdx.x, tid = threadIdx.x;
  __shared__ float red[256];
  const float* m = (i < N_L) ? mLs : mUs;
  const float scale = (i < N_L) ? (1.0f / 500.0f) : (1.0f / 1500.0f);
  float* z = Z + (size_t)i * DD;
  float s = 0.f;
  for (int k = tid; k < DD; k += 256) { float v = z[k] - m[k] * scale; s += v * v; }
  red[tid] = s; __syncthreads();
  for (int o = 128; o > 0; o >>= 1) { if (tid < o) red[tid] += red[tid + o]; __syncthreads(); }
  float inv = 1.0f / fmaxf(sqrtf(red[0]), 1e-12f);
  for (int k = tid; k < DD; k += 256) z[k] = (z[k] - m[k] * scale) * inv;
}

__global__ __launch_bounds__(256) void k_musinit(const float* __restrict__ Z, float* __restrict__ SL,
                                                 float* __restrict__ mus, float* __restrict__ musq,
                                                 short* __restrict__ musb, float* __restrict__ binit) {
  int w = blockIdx.x, tid = threadIdx.x;
  __shared__ float red[256];
  if (tid == 0) binit[w] = 1.0f;
  float q = 0.f;
  for (int k = tid; k < DD; k += 256) {
    float s = 0.f;
    for (int sh = 0; sh < SHOT; ++sh) s += Z[(size_t)(sh * WAY + w) * DD + k];
    SL[(size_t)w * DD + k] = s;
    float m = s / 5.0f;
    mus[(size_t)w * DD + k] = m;
    musb[(size_t)w * DD + k] = f2bs(m);
    q += m * m;
  }
  red[tid] = q; __syncthreads();
  for (int o = 128; o > 0; o >>= 1) { if (tid < o) red[tid] += red[tid + o]; __syncthreads(); }
  if (tid == 0) musq[w] = red[0];
}

// ---- one-time: Zu -> bf16 row-major (rows 1500..1535 zeroed) ----
__global__ __launch_bounds__(256) void k_zb(const float* __restrict__ Z, short* __restrict__ Zb) {
  size_t i0 = ((size_t)blockIdx.x * 256 + threadIdx.x) * 8;   // 3072 blocks: 1536*4096 elems
  short8_t v;
  if (i0 < (size_t)N_U * DD) {
    const float* src = Z + (size_t)N_L * DD + i0;
    float4 a = *(const float4*)src;
    float4 b = *(const float4*)(src + 4);
    v[0] = f2bs(a.x); v[1] = f2bs(a.y); v[2] = f2bs(a.z); v[3] = f2bs(a.w);
    v[4] = f2bs(b.x); v[5] = f2bs(b.y); v[6] = f2bs(b.z); v[7] = f2bs(b.w);
  } else {
    v = (short8_t){0, 0, 0, 0, 0, 0, 0, 0};
  }
  *(short8_t*)(Zb + i0) = v;
}

// ---- one-time: Zu^T bf16 (4096 x 1536, cols 1500..1535 zeroed) ----
__global__ __launch_bounds__(256) void k_zt(const float* __restrict__ Z, short* __restrict__ ZuT) {
  __shared__ float tile[32][33];
  int k0 = blockIdx.x * 32, u0 = blockIdx.y * 32;
  int c = threadIdx.x & 31, r0 = threadIdx.x >> 5;
#pragma unroll
  for (int rr = 0; rr < 4; ++rr) {
    int r = r0 + rr * 8;
    int u = u0 + r;
    tile[r][c] = (u < N_U) ? Z[(size_t)(N_L + u) * DD + k0 + c] : 0.f;
  }
  __syncthreads();
#pragma unroll
  for (int rr = 0; rr < 4; ++rr) {
    int r = r0 + rr * 8;
    ZuT[(size_t)(k0 + r) * PTS + u0 + c] = f2bs(tile[c][r]);
  }
}

// ---------------- GEMM1 (MFMA): D2PT[sp][w][u] partials of mus.Zu^T ----------------
__global__ __launch_bounds__(256) void k_gemm1(const short* __restrict__ Zb, const short* __restrict__ musb,
                                               float* __restrict__ D2PT, float* __restrict__ cols,
                                               unsigned* __restrict__ miscz) {
  int tid = threadIdx.x;
  if (blockIdx.x == 0 && blockIdx.y == 0) {
    for (int z = tid; z < 9600; z += 256) cols[z] = 0.f;
    if (tid < 4) miscz[tid] = 0u;            // errG[0..2] + KsumG
  }
  int wv = tid >> 6;
  int l = tid & 63;
  int l15 = l & 15, quad = l >> 4;
  int u0 = blockIdx.x * 64 + wv * 16;
  int kz = blockIdx.y * G1_KLEN;
  f32x4 acc[7];
#pragma unroll
  for (int c = 0; c < 7; ++c) acc[c] = (f32x4){0.f, 0.f, 0.f, 0.f};

  const short* bp = Zb + (size_t)(u0 + l15) * DD + kz + quad * 8;
  const short* ap = musb + (size_t)l15 * DD + kz + quad * 8;

#pragma unroll 2
  for (int kc = 0; kc < G1_KLEN; kc += 32) {
    short8_t bf = *(const short8_t*)(bp + kc);
#pragma unroll
    for (int c = 0; c < 7; ++c) {
      short8_t af = *(const short8_t*)(ap + (size_t)c * 16 * DD + kc);
      acc[c] = __builtin_amdgcn_mfma_f32_16x16x32_bf16(af, bf, acc[c], 0, 0, 0);
    }
  }
  float* dst = D2PT + (size_t)blockIdx.y * D2P_STRIDE;
#pragma unroll
  for (int c = 0; c < 7; ++c)
#pragma unroll
    for (int r = 0; r < 4; ++r)
      dst[(size_t)(16 * c + quad * 4 + r) * PTS + u0 + l15] = acc[c][r];
}

// ---------------- reduce splits -> K = exp(-lam*dist) ----------------
__global__ __launch_bounds__(256) void k_expK(const float* __restrict__ D2PT, const float* __restrict__ musq,
                                              float* __restrict__ Kmat) {
  int w = blockIdx.y;
  int u = blockIdx.x * 256 + threadIdx.x;
  if (u < N_U) {
    float s = 0.f;
#pragma unroll
    for (int sp = 0; sp < G1_SPLIT; ++sp) s += D2PT[(size_t)sp * D2P_STRIDE + (size_t)w * PTS + u];
    float d2 = 1.0f + musq[w] - 2.0f * s;
    Kmat[(size_t)u * WAY + w] = expf(-LAMF * sqrtf(fmaxf(d2, 1e-12f)));
  }
}

// ---------------- sinkhorn (8 blocks, device-scope barrier) ----------------
__device__ __forceinline__ void grid_barrier(unsigned* cnt, unsigned* gen, unsigned nb) {
  __syncthreads();
  if (threadIdx.x == 0) {
    __threadfence();
    unsigned g = __hip_atomic_load(gen, __ATOMIC_RELAXED, __HIP_MEMORY_SCOPE_AGENT);
    unsigned a = __hip_atomic_fetch_add(cnt, 1u, __ATOMIC_ACQ_REL, __HIP_MEMORY_SCOPE_AGENT);
    if (a == nb - 1u) {
      __hip_atomic_store(cnt, 0u, __ATOMIC_RELAXED, __HIP_MEMORY_SCOPE_AGENT);
      __hip_atomic_fetch_add(gen, 1u, __ATOMIC_RELEASE, __HIP_MEMORY_SCOPE_AGENT);
    } else {
      while (__hip_atomic_load(gen, __ATOMIC_ACQUIRE, __HIP_MEMORY_SCOPE_AGENT) == g) {
        __builtin_amdgcn_s_sleep(1);
      }
    }
    __threadfence();
  }
  __syncthreads();
}

__global__ __launch_bounds__(256) void k_sink(const float* __restrict__ Kg, float* __restrict__ Pg,
                                              short* __restrict__ PT, float* __restrict__ cols,
                                              float* __restrict__ binit, unsigned* __restrict__ misc_u,
                                              float* __restrict__ misc_f) {
  __shared__ float Kl[RPB * KLP];                // 188*101*4 = 75952 B
  __shared__ float a[RPB], aold[RPB], prevs[RPB], b[WAY];
  __shared__ float rerr[256];
  __shared__ float c2[2 * WAY];
  __shared__ float red[256];
  unsigned* errG = misc_u;
  float* KsumG = misc_f + 3;
  unsigned* cnt = misc_u + 4;
  unsigned* gen = misc_u + 5;
  int tid = threadIdx.x;
  int row0 = blockIdx.x * RPB;
  int nrows = (row0 + RPB <= N_U) ? RPB : (N_U - row0);   // last block: 184

  float ks = 0.f;
  for (int idx = tid; idx < nrows * WAY; idx += 256) {
    float v = Kg[row0 * WAY + idx];
    int r = idx / WAY, j = idx - r * WAY;
    Kl[r * KLP + j] = v; ks += v;
  }
  red[tid] = ks; __syncthreads();
  for (int o = 128; o > 0; o >>= 1) { if (tid < o) red[tid] += red[tid + o]; __syncthreads(); }
  if (tid == 0) atomicAdd(KsumG, red[0]);
  if (tid < RPB) prevs[tid] = 0.f;
  if (tid < WAY) b[tid] = binit[tid];     // warm start (semantics-neutral; measured neutral on iters)
  grid_barrier(cnt, gen, SINK_BLOCKS);
  float S = *KsumG;
  if (tid < RPB) a[tid] = 1.0f / S;   // folds K/K.sum() into a exactly

  bool conv = false;
  for (int t = 0; t < MAXIT; ++t) {
    int buf = t % 3;
    int zb = (t + 1) % 3;
    __syncthreads();
    if (tid < nrows) {
      const float* kr = &Kl[tid * KLP];
      float r0 = 0.f, r1 = 0.f, r2 = 0.f, r3 = 0.f;
#pragma unroll 4
      for (int j = 0; j < WAY; j += 4) {
        r0 = fmaf(kr[j], b[j], r0);
        r1 = fmaf(kr[j + 1], b[j + 1], r1);
        r2 = fmaf(kr[j + 2], b[j + 2], r2);
        r3 = fmaf(kr[j + 3], b[j + 3], r3);
      }
      float rs = ((r0 + r1) + (r2 + r3)) * a[tid];
      rerr[tid] = fabsf(prevs[tid] - rs);
      aold[tid] = a[tid];
      a[tid] = a[tid] / rs;                // speculative; rolled back on convergence
      prevs[tid] = rs;
    } else {
      rerr[tid] = 0.f;
    }
    __syncthreads();
    {
      int j = -1, rlo = 0, rhi = 0, slot = 0;
      if (tid < WAY) { j = tid; rlo = 0; rhi = 94; slot = 0; }
      else if (tid >= 128 && tid < 128 + WAY) { j = tid - 128; rlo = 94; rhi = RPB; slot = 1; }
      if (j >= 0) {
        if (rhi > nrows) rhi = nrows;
        float pc = 0.f;
        for (int r = rlo; r < rhi; ++r) pc = fmaf(Kl[r * KLP + j], a[r], pc);
        c2[slot * WAY + j] = pc;
      }
    }
    __syncthreads();
    if (tid < WAY) atomicAdd(&cols[buf * 3200 + tid * 32], c2[tid] + c2[WAY + tid]);
    if (blockIdx.x == 0) {
      if (tid < WAY) cols[zb * 3200 + tid * 32] = 0.f;
      if (tid == 0) __hip_atomic_store(&errG[zb], 0u, __ATOMIC_RELAXED, __HIP_MEMORY_SCOPE_AGENT);
    }
    if (tid < 64) {
      float m = fmaxf(fmaxf(rerr[tid], rerr[tid + 64]), fmaxf(rerr[tid + 128], rerr[tid + 192]));
#pragma unroll
      for (int o = 32; o > 0; o >>= 1) m = fmaxf(m, __shfl_down(m, o));
      if (tid == 0) atomicMax(&errG[buf], __float_as_uint(m));
    }
    grid_barrier(cnt, gen, SINK_BLOCKS);
    unsigned eu = __hip_atomic_load(&errG[buf], __ATOMIC_RELAXED, __HIP_MEMORY_SCOPE_AGENT);
    if (__uint_as_float(eu) <= EPSF) { conv = true; break; }
    if (tid < WAY) b[tid] = (float)NQ / cols[buf * 3200 + tid * 32];
  }
  __syncthreads();
  // P fp32 row-major (for k_final / readability of final epoch)
  for (int idx = tid; idx < nrows * WAY; idx += 256) {
    int r = idx / WAY; int j = idx - r * WAY;
    float av = conv ? aold[r] : a[r];
    Pg[row0 * WAY + idx] = av * Kl[r * KLP + j] * b[j];
  }
  // P^T bf16 (A-operand for gemm2), coalesced in u
  for (int idx = tid; idx < WAY * nrows; idx += 256) {
    int j = idx / nrows; int r = idx - j * nrows;
    float av = conv ? aold[r] : a[r];
    PT[(size_t)j * PTS + row0 + r] = f2bs(av * Kl[r * KLP + j] * b[j]);
  }
  if (blockIdx.x == SINK_BLOCKS - 1) {           // zero PT tail cols 1500..1503 (K-loop reads u<1504)
    for (int idx = tid; idx < WAY * 4; idx += 256) {
      int j = idx >> 2; PT[(size_t)j * PTS + 1500 + (idx & 3)] = 0;
    }
  }
  if (blockIdx.x == 0 && tid < WAY) binit[tid] = b[tid];
}

// ---------------- GEMM2 (MFMA): CP[w][k] = sum_u PT[w][u] * ZuT[k][u] ----------------
__global__ __launch_bounds__(64) void k_gemm2(const short* __restrict__ PT, const short* __restrict__ ZuT,
                                              float* __restrict__ CP) {
  int l = threadIdx.x;
  int l15 = l & 15, quad = l >> 4;
  int k0 = blockIdx.x * 16;                      // 256 blocks
  f32x4 acc[7];
#pragma unroll
  for (int c = 0; c < 7; ++c) acc[c] = (f32x4){0.f, 0.f, 0.f, 0.f};
  const short* ap = PT + (size_t)l15 * PTS + quad * 8;
  const short* bp = ZuT + (size_t)(k0 + l15) * PTS + quad * 8;
#pragma unroll 2
  for (int kc = 0; kc < 1504; kc += 32) {
    short8_t bf = *(const short8_t*)(bp + kc);
#pragma unroll
    for (int c = 0; c < 7; ++c) {
      short8_t af = *(const short8_t*)(ap + (size_t)c * 16 * PTS + kc);
      acc[c] = __builtin_amdgcn_mfma_f32_16x16x32_bf16(af, bf, acc[c], 0, 0, 0);
    }
  }
#pragma unroll
  for (int c = 0; c < 7; ++c)
#pragma unroll
    for (int r = 0; r < 4; ++r)
      CP[(size_t)(16 * c + quad * 4 + r) * DD + k0 + l15] = acc[c][r];
}

// ---------------- mus update + musq (+ bf16 mus for gemm1) ----------------
__global__ __launch_bounds__(256) void k_musup(const float* __restrict__ musR, const float* __restrict__ SL,
                                               const float* __restrict__ CP, float* __restrict__ musW,
                                               float* __restrict__ musq, short* __restrict__ musb) {
  int w = blockIdx.x, tid = threadIdx.x;
  __shared__ float red[256];
  float q = 0.f;
  for (int k = tid; k < DD; k += 256) {
    size_t o = (size_t)w * DD + k;
    float emus = (SL[o] + CP[o]) / 20.0f;   // p.sum(0) == 5 + 15 exactly
    float m = musR[o];
    float v = m + 0.2f * (emus - m);
    musW[o] = v;
    musb[o] = f2bs(v);
    q += v * v;
  }
  red[tid] = q; __syncthreads();
  for (int o = 128; o > 0; o >>= 1) { if (tid < o) red[tid] += red[tid + o]; __syncthreads(); }
  if (tid == 0) musq[w] = red[0];
}

// ---------------- final logP + acc ----------------
__global__ __launch_bounds__(128) void k_final(const float* __restrict__ Pg, const int* __restrict__ labels,
                                               float* __restrict__ out, unsigned* __restrict__ ctr) {
  int u = blockIdx.x, tid = threadIdx.x;
  __shared__ float vals[WAY];
  if (tid < WAY) {
    float v = Pg[(size_t)u * WAY + tid];
    vals[tid] = v;
    out[(size_t)u * WAY + tid] = logf(v + 1e-5f);
  }
  __syncthreads();
  if (tid == 0) {
    int am = 0; float bv = vals[0];
    for (int j = 1; j < WAY; ++j) { if (vals[j] > bv) { bv = vals[j]; am = j; } }
    if (am == labels[N_L + u]) atomicAdd(ctr, 1u);
  }
}

__global__ void k_acc(const unsigned* __restrict__ ctr, float* __restrict__ out) {
  if (threadIdx.x == 0) out[N_U * WAY] = (float)(*ctr) / 1500.0f;
}

// ---------------- host ----------------
extern "C" void kernel_launch(void* const* d_in, const int* in_sizes, int n_in,
                              void* d_out, int out_size, void* d_ws, size_t ws_size,
                              hipStream_t stream) {
  const float* X = (const float*)d_in[0];
  const int* labels = (const int*)d_in[1];
  float* out = (float*)d_out;
  float* ws = (float*)d_ws;

  float* Z     = ws + OFF_Z;
  short* Zb    = (short*)(ws + OFF_Z);       // overlays labeled Z rows (dead after musinit)
  float* meanL = ws + OFF_MEANL;
  float* meanU = ws + OFF_MEANU;
  float* binit = ws + OFF_MEANL;             // meanL dead after k_center
  float* SL    = ws + OFF_SL;
  float* musA  = ws + OFF_MUSA;
  float* musB  = ws + OFF_MUSB;
  float* musq  = ws + OFF_MUSQ;
  short* musb16 = (short*)(ws + OFF_MUSB16);
  short* PT    = (short*)(ws + OFF_PT);
  float* Kmat  = ws + OFF_KMAT;
  float* Pmat  = ws + OFF_PMAT;
  float* cols  = ws + OFF_COLS;
  float* misc_f = ws + OFF_MISC;
  unsigned* misc_u = (unsigned*)(ws + OFF_MISC);
  short* ZuT   = (short*)(ws + OFF_ZUT);
  float* D2PT  = ws + OFF_D2P;
  float* CP    = ws + OFF_D2P;               // overlaid: disjoint lifetimes within an epoch

  k_pow_norm<<<N_TOT, 256, 0, stream>>>(X, Z, meanL, misc_u);
  k_colmeans<<<dim3(16, 25), 256, 0, stream>>>(Z, meanL, meanU);
  k_center<<<N_TOT, 256, 0, stream>>>(Z, meanL, meanU);
  k_musinit<<<WAY, 256, 0, stream>>>(Z, SL, musA, musq, musb16, binit);
  k_zt<<<dim3(128, 48), 256, 0, stream>>>(Z, ZuT);
  k_zb<<<3072, 256, 0, stream>>>(Z, Zb);     // must run after k_zt (k_zt reads fp32 Z; Zb overlays Z[0:500])

  float* musR = musA;
  float* musW = musB;
  for (int e = 0; e < 20; ++e) {
    k_gemm1<<<dim3(24, G1_SPLIT), 256, 0, stream>>>(Zb, musb16, D2PT, cols, misc_u);
    k_expK<<<dim3(6, WAY), 256, 0, stream>>>(D2PT, musq, Kmat);
    k_sink<<<SINK_BLOCKS, 256, 0, stream>>>(Kmat, Pmat, PT, cols, binit, misc_u, misc_f);
    k_gemm2<<<256, 64, 0, stream>>>(PT, ZuT, CP);
    k_musup<<<WAY, 256, 0, stream>>>(musR, SL, CP, musW, musq, musb16);
    float* tmp = musR; musR = musW; musW = tmp;
  }
  k_gemm1<<<dim3(24, G1_SPLIT), 256, 0, stream>>>(Zb, musb16, D2PT, cols, misc_u);
  k_expK<<<dim3(6, WAY), 256, 0, stream>>>(D2PT, musq, Kmat);
  k_sink<<<SINK_BLOCKS, 256, 0, stream>>>(Kmat, Pmat, PT, cols, binit, misc_u, misc_f);
  k_final<<<N_U, 128, 0, stream>>>(Pmat, labels, out, misc_u + 6);
  k_acc<<<1, 64, 0, stream>>>(misc_u + 6, out);
}

// Round 6
// 2477.025 us; speedup vs baseline: 1.0708x; 1.0708x over previous
//
#include <hip/hip_runtime.h>

#define WAY   100
#define SHOT  5
#define NQ    15
#define DD    4096
#define N_L   500
#define N_U   1500
#define N_TOT 2000
#define LAMF  10.0f
#define EPSF  1e-6f
#define MAXIT 1000

// ---- workspace layout (float offsets) ----
#define OFF_Z      0u          // Z fp32 2000*4096; labeled half dead after musinit -> Zb bf16 overlay
#define OFF_MEANL  8192000u    // 4096 col sums; binit(100) after k_center
#define OFF_MEANU  8196096u    // 4096
#define OFF_SL     8200192u    // 100*4096
#define OFF_MUSA   8609792u    // 112*4096
#define OFF_MUSB   9068544u    // 112*4096
#define OFF_MUSQ   9527296u    // 128
#define OFF_MUSB16 9527424u    // bf16 mus 112*4096 sh = 229376 fl
#define OFF_PTH    9756800u    // bf16 P^T hi 112*1536 sh = 86016 fl
#define OFF_PTL    9842816u    // bf16 P^T lo 112*1536 sh = 86016 fl
#define OFF_KMAT   9928832u    // 150000
#define OFF_COLS   10078832u   // 3*100*32 = 9600
#define OFF_MISC   10088432u   // [0..2]=err3(u), [3]=Ksum(f), [4]=cnt(u), [5]=gen(u), [6]=ctr(u)
#define OFF_ZUT    10088464u   // bf16 Zu^T 4096*1536 sh = 1572864 fl
#define OFF_D2P    11661328u   // 8*172032 = 1376256 fl (shared with CP 112*4096) -> ends 13037584

#define G1_SPLIT 8
#define G1_KLEN  512           // 4096/8
#define D2P_STRIDE 172032u     // 112*1536
#define SINK_BLOCKS 16         // R5 lesson: fewer blocks -> longer serial col phase; 16 is the sweet spot
#define RPB 94
#define KLP 108                // 108*4=432B rows: 16B-aligned (b128 ok), bank step 27 (coprime 32)
#define PTS 1536

typedef __attribute__((ext_vector_type(8))) short short8_t;
typedef __attribute__((ext_vector_type(4))) float f32x4;

// fp32 -> bf16 bits, round-to-nearest-even
__device__ __forceinline__ short f2bs(float f) {
  unsigned u = __float_as_uint(f);
  unsigned r = (u + 0x7FFFu + ((u >> 16) & 1u)) >> 16;
  return (short)r;
}
__device__ __forceinline__ float bs2f(short s) {
  return __uint_as_float(((unsigned)(unsigned short)s) << 16);
}

// ---------------- preprocessing ----------------
__global__ __launch_bounds__(256) void k_pow_norm(const float* __restrict__ X, float* __restrict__ Z,
                                                  float* __restrict__ msums, unsigned* __restrict__ misc_u) {
  int i = blockIdx.x, tid = threadIdx.x;
  __shared__ float red[256];
  if (i < 32) msums[i * 256 + tid] = 0.f;
  if (i == 32 && tid < 16) misc_u[tid] = 0u;
  const float* x = X + (size_t)i * DD;
  float s = 0.f;
  for (int k = tid; k < DD; k += 256) s += x[k] + 1e-6f;
  red[tid] = s; __syncthreads();
  for (int o = 128; o > 0; o >>= 1) { if (tid < o) red[tid] += red[tid + o]; __syncthreads(); }
  float inv = 1.0f / fmaxf(sqrtf(red[0]), 1e-12f);
  float* z = Z + (size_t)i * DD;
  for (int k = tid; k < DD; k += 256) z[k] = sqrtf(x[k] + 1e-6f) * inv;
}

__global__ __launch_bounds__(256) void k_colmeans(const float* __restrict__ Z, float* __restrict__ mLs,
                                                  float* __restrict__ mUs) {
  int k = blockIdx.x * 256 + threadIdx.x;
  int r0 = blockIdx.y * 80;
  float sL = 0.f, sU = 0.f;
  for (int r = r0; r < r0 + 80; ++r) {
    float v = Z[(size_t)r * DD + k];
    if (r < N_L) sL += v; else sU += v;
  }
  if (r0 < N_L) atomicAdd(&mLs[k], sL);
  if (r0 + 80 > N_L) atomicAdd(&mUs[k], sU);
}

__global__ __launch_bounds__(256) void k_center(float* __restrict__ Z, const float* __restrict__ mLs,
                                                const float* __restrict__ mUs) {
  int i = blockIdx.x, tid = threadIdx.x;
  __shared__ float red[256];
  const float* m = (i < N_L) ? mLs : mUs;
  const float scale = (i < N_L) ? (1.0f / 500.0f) : (1.0f / 1500.0f);
  float* z = Z + (size_t)i * DD;
  float s = 0.f;
  for (int k = tid; k < DD; k += 256) { float v = z[k] - m[k] * scale; s += v * v; }
  red[tid] = s; __syncthreads();
  for (int o = 128; o > 0; o >>= 1) { if (tid < o) red[tid] += red[tid + o]; __syncthreads(); }
  float inv = 1.0f / fmaxf(sqrtf(red[0]), 1e-12f);
  for (int k = tid; k < DD; k += 256) z[k] = (z[k] - m[k] * scale) * inv;
}

__global__ __launch_bounds__(256) void k_musinit(const float* __restrict__ Z, float* __restrict__ SL,
                                                 float* __restrict__ mus, float* __restrict__ musq,
                                                 short* __restrict__ musb, float* __restrict__ binit) {
  int w = blockIdx.x, tid = threadIdx.x;
  __shared__ float red[256];
  if (tid == 0) binit[w] = 1.0f;
  float q = 0.f;
  for (int k = tid; k < DD; k += 256) {
    float s = 0.f;
    for (int sh = 0; sh < SHOT; ++sh) s += Z[(size_t)(sh * WAY + w) * DD + k];
    SL[(size_t)w * DD + k] = s;
    float m = s / 5.0f;
    mus[(size_t)w * DD + k] = m;
    musb[(size_t)w * DD + k] = f2bs(m);
    q += m * m;
  }
  red[tid] = q; __syncthreads();
  for (int o = 128; o > 0; o >>= 1) { if (tid < o) red[tid] += red[tid + o]; __syncthreads(); }
  if (tid == 0) musq[w] = red[0];
}

// ---- one-time: Zu -> bf16 row-major (rows 1500..1535 zeroed) ----
__global__ __launch_bounds__(256) void k_zb(const float* __restrict__ Z, short* __restrict__ Zb) {
  size_t i0 = ((size_t)blockIdx.x * 256 + threadIdx.x) * 8;
  short8_t v;
  if (i0 < (size_t)N_U * DD) {
    const float* src = Z + (size_t)N_L * DD + i0;
    float4 a = *(const float4*)src;
    float4 b = *(const float4*)(src + 4);
    v[0] = f2bs(a.x); v[1] = f2bs(a.y); v[2] = f2bs(a.z); v[3] = f2bs(a.w);
    v[4] = f2bs(b.x); v[5] = f2bs(b.y); v[6] = f2bs(b.z); v[7] = f2bs(b.w);
  } else {
    v = (short8_t){0, 0, 0, 0, 0, 0, 0, 0};
  }
  *(short8_t*)(Zb + i0) = v;
}

// ---- one-time: Zu^T bf16 (4096 x 1536, cols 1500..1535 zeroed) ----
__global__ __launch_bounds__(256) void k_zt(const float* __restrict__ Z, short* __restrict__ ZuT) {
  __shared__ float tile[32][33];
  int k0 = blockIdx.x * 32, u0 = blockIdx.y * 32;
  int c = threadIdx.x & 31, r0 = threadIdx.x >> 5;
#pragma unroll
  for (int rr = 0; rr < 4; ++rr) {
    int r = r0 + rr * 8;
    int u = u0 + r;
    tile[r][c] = (u < N_U) ? Z[(size_t)(N_L + u) * DD + k0 + c] : 0.f;
  }
  __syncthreads();
#pragma unroll
  for (int rr = 0; rr < 4; ++rr) {
    int r = r0 + rr * 8;
    ZuT[(size_t)(k0 + r) * PTS + u0 + c] = f2bs(tile[c][r]);
  }
}

// ---------------- GEMM1 (MFMA): D2PT[sp][w][u] partials of mus.Zu^T ----------------
__global__ __launch_bounds__(256) void k_gemm1(const short* __restrict__ Zb, const short* __restrict__ musb,
                                               float* __restrict__ D2PT, float* __restrict__ cols,
                                               unsigned* __restrict__ miscz) {
  int tid = threadIdx.x;
  if (blockIdx.x == 0 && blockIdx.y == 0) {
    for (int z = tid; z < 9600; z += 256) cols[z] = 0.f;
    if (tid < 4) miscz[tid] = 0u;            // errG[0..2] + KsumG
  }
  int wv = tid >> 6;
  int l = tid & 63;
  int l15 = l & 15, quad = l >> 4;
  int u0 = blockIdx.x * 64 + wv * 16;
  int kz = blockIdx.y * G1_KLEN;
  f32x4 acc[7];
#pragma unroll
  for (int c = 0; c < 7; ++c) acc[c] = (f32x4){0.f, 0.f, 0.f, 0.f};

  const short* bp = Zb + (size_t)(u0 + l15) * DD + kz + quad * 8;
  const short* ap = musb + (size_t)l15 * DD + kz + quad * 8;

#pragma unroll 2
  for (int kc = 0; kc < G1_KLEN; kc += 32) {
    short8_t bf = *(const short8_t*)(bp + kc);
#pragma unroll
    for (int c = 0; c < 7; ++c) {
      short8_t af = *(const short8_t*)(ap + (size_t)c * 16 * DD + kc);
      acc[c] = __builtin_amdgcn_mfma_f32_16x16x32_bf16(af, bf, acc[c], 0, 0, 0);
    }
  }
  float* dst = D2PT + (size_t)blockIdx.y * D2P_STRIDE;
#pragma unroll
  for (int c = 0; c < 7; ++c)
#pragma unroll
    for (int r = 0; r < 4; ++r)
      dst[(size_t)(16 * c + quad * 4 + r) * PTS + u0 + l15] = acc[c][r];
}

// ---------------- reduce splits -> K = exp(-lam*dist) ----------------
__global__ __launch_bounds__(256) void k_expK(const float* __restrict__ D2PT, const float* __restrict__ musq,
                                              float* __restrict__ Kmat) {
  int w = blockIdx.y;
  int u = blockIdx.x * 256 + threadIdx.x;
  if (u < N_U) {
    float s = 0.f;
#pragma unroll
    for (int sp = 0; sp < G1_SPLIT; ++sp) s += D2PT[(size_t)sp * D2P_STRIDE + (size_t)w * PTS + u];
    float d2 = 1.0f + musq[w] - 2.0f * s;
    Kmat[(size_t)u * WAY + w] = expf(-LAMF * sqrtf(fmaxf(d2, 1e-12f)));
  }
}

// ---------------- sinkhorn (16 blocks, device-scope barrier) ----------------
__device__ __forceinline__ void grid_barrier(unsigned* cnt, unsigned* gen, unsigned nb) {
  __syncthreads();
  if (threadIdx.x == 0) {
    __threadfence();
    unsigned g = __hip_atomic_load(gen, __ATOMIC_RELAXED, __HIP_MEMORY_SCOPE_AGENT);
    unsigned a = __hip_atomic_fetch_add(cnt, 1u, __ATOMIC_ACQ_REL, __HIP_MEMORY_SCOPE_AGENT);
    if (a == nb - 1u) {
      __hip_atomic_store(cnt, 0u, __ATOMIC_RELAXED, __HIP_MEMORY_SCOPE_AGENT);
      __hip_atomic_fetch_add(gen, 1u, __ATOMIC_RELEASE, __HIP_MEMORY_SCOPE_AGENT);
    } else {
      while (__hip_atomic_load(gen, __ATOMIC_ACQUIRE, __HIP_MEMORY_SCOPE_AGENT) == g) {
        __builtin_amdgcn_s_sleep(1);
      }
    }
    __threadfence();
  }
  __syncthreads();
}

__global__ __launch_bounds__(256) void k_sink(const float* __restrict__ Kg,
                                              short* __restrict__ PTH, short* __restrict__ PTL,
                                              float* __restrict__ cols, float* __restrict__ binit,
                                              unsigned* __restrict__ misc_u, float* __restrict__ misc_f) {
  __shared__ float Kl[RPB * KLP];                // 94*108*4 = 40608 B, rows 16B-aligned
  __shared__ float a[RPB], aold[RPB], prevs[RPB], b[WAY];
  __shared__ float rerr[256];
  __shared__ float c2[2 * WAY];
  __shared__ float red[256];
  unsigned* errG = misc_u;
  float* KsumG = misc_f + 3;
  unsigned* cnt = misc_u + 4;
  unsigned* gen = misc_u + 5;
  int tid = threadIdx.x;
  int row0 = blockIdx.x * RPB;
  int nrows = (row0 + RPB <= N_U) ? RPB : (N_U - row0);   // last block: 90

  float ks = 0.f;
  for (int idx = tid; idx < nrows * WAY; idx += 256) {
    float v = Kg[row0 * WAY + idx];
    int r = idx / WAY, j = idx - r * WAY;
    Kl[r * KLP + j] = v; ks += v;
  }
  red[tid] = ks; __syncthreads();
  for (int o = 128; o > 0; o >>= 1) { if (tid < o) red[tid] += red[tid + o]; __syncthreads(); }
  if (tid == 0) atomicAdd(KsumG, red[0]);
  if (tid < RPB) prevs[tid] = 0.f;
  if (tid < WAY) b[tid] = binit[tid];     // warm start (semantics-neutral)
  grid_barrier(cnt, gen, SINK_BLOCKS);
  float S = *KsumG;
  if (tid < RPB) a[tid] = 1.0f / S;       // folds K/K.sum() into a exactly

  bool conv = false;
  for (int t = 0; t < MAXIT; ++t) {
    int buf = t % 3;
    int zb = (t + 1) % 3;
    __syncthreads();
    if (tid < nrows) {
      const float* kr = &Kl[tid * KLP];
      float r0 = 0.f, r1 = 0.f, r2 = 0.f, r3 = 0.f;
#pragma unroll 4
      for (int j = 0; j < WAY; j += 4) {
        r0 = fmaf(kr[j], b[j], r0);
        r1 = fmaf(kr[j + 1], b[j + 1], r1);
        r2 = fmaf(kr[j + 2], b[j + 2], r2);
        r3 = fmaf(kr[j + 3], b[j + 3], r3);
      }
      float rs = ((r0 + r1) + (r2 + r3)) * a[tid];
      rerr[tid] = fabsf(prevs[tid] - rs);
      aold[tid] = a[tid];
      a[tid] = a[tid] / rs;                // speculative; rolled back on convergence
      prevs[tid] = rs;
    } else {
      rerr[tid] = 0.f;
    }
    __syncthreads();
    {
      int j = -1, rlo = 0, rhi = 0, slot = 0;
      if (tid < WAY) { j = tid; rlo = 0; rhi = 47; slot = 0; }
      else if (tid >= 128 && tid < 128 + WAY) { j = tid - 128; rlo = 47; rhi = RPB; slot = 1; }
      if (j >= 0) {
        if (rhi > nrows) rhi = nrows;
        float pc = 0.f;
        for (int r = rlo; r < rhi; ++r) pc = fmaf(Kl[r * KLP + j], a[r], pc);
        c2[slot * WAY + j] = pc;
      }
    }
    __syncthreads();
    if (tid < WAY) atomicAdd(&cols[buf * 3200 + tid * 32], c2[tid] + c2[WAY + tid]);
    if (blockIdx.x == 0) {
      if (tid < WAY) cols[zb * 3200 + tid * 32] = 0.f;
      if (tid == 0) __hip_atomic_store(&errG[zb], 0u, __ATOMIC_RELAXED, __HIP_MEMORY_SCOPE_AGENT);
    }
    if (tid < 64) {
      float m = fmaxf(fmaxf(rerr[tid], rerr[tid + 64]), fmaxf(rerr[tid + 128], rerr[tid + 192]));
#pragma unroll
      for (int o = 32; o > 0; o >>= 1) m = fmaxf(m, __shfl_down(m, o));
      if (tid == 0) atomicMax(&errG[buf], __float_as_uint(m));
    }
    grid_barrier(cnt, gen, SINK_BLOCKS);
    unsigned eu = __hip_atomic_load(&errG[buf], __ATOMIC_RELAXED, __HIP_MEMORY_SCOPE_AGENT);
    if (__uint_as_float(eu) <= EPSF) { conv = true; break; }
    if (tid < WAY) b[tid] = (float)NQ / cols[buf * 3200 + tid * 32];
  }
  __syncthreads();
  // P^T hi/lo bf16 (A-operand for gemm2 + k_final source), coalesced in u
  for (int idx = tid; idx < WAY * nrows; idx += 256) {
    int j = idx / nrows; int r = idx - j * nrows;
    float av = conv ? aold[r] : a[r];
    float p = av * Kl[r * KLP + j] * b[j];
    short hi = f2bs(p);
    PTH[(size_t)j * PTS + row0 + r] = hi;
    PTL[(size_t)j * PTS + row0 + r] = f2bs(p - bs2f(hi));
  }
  if (blockIdx.x == SINK_BLOCKS - 1) {     // zero cols 1500..1503 (gemm2 K loop reads u<1504)
    for (int idx = tid; idx < WAY * 4; idx += 256) {
      int j = idx >> 2;
      PTH[(size_t)j * PTS + 1500 + (idx & 3)] = 0;
      PTL[(size_t)j * PTS + 1500 + (idx & 3)] = 0;
    }
  }
  if (blockIdx.x == 0 && tid < WAY) binit[tid] = b[tid];
}

// ---------------- GEMM2 (MFMA, double-bf16 P): CP[w][k] = sum_u (PTh+PTl)[w][u] * ZuT[k][u] ------
__global__ __launch_bounds__(64) void k_gemm2(const short* __restrict__ PTH, const short* __restrict__ PTL,
                                              const short* __restrict__ ZuT, float* __restrict__ CP) {
  int l = threadIdx.x;
  int l15 = l & 15, quad = l >> 4;
  int k0 = blockIdx.x * 16;                      // 256 blocks
  f32x4 acc[7];
#pragma unroll
  for (int c = 0; c < 7; ++c) acc[c] = (f32x4){0.f, 0.f, 0.f, 0.f};
  size_t aoff = (size_t)l15 * PTS + quad * 8;
  const short* bp = ZuT + (size_t)(k0 + l15) * PTS + quad * 8;
#pragma unroll 2
  for (int kc = 0; kc < 1504; kc += 32) {
    short8_t bf = *(const short8_t*)(bp + kc);
#pragma unroll
    for (int c = 0; c < 7; ++c) {
      short8_t ah = *(const short8_t*)(PTH + aoff + (size_t)c * 16 * PTS + kc);
      short8_t al = *(const short8_t*)(PTL + aoff + (size_t)c * 16 * PTS + kc);
      acc[c] = __builtin_amdgcn_mfma_f32_16x16x32_bf16(ah, bf, acc[c], 0, 0, 0);
      acc[c] = __builtin_amdgcn_mfma_f32_16x16x32_bf16(al, bf, acc[c], 0, 0, 0);
    }
  }
#pragma unroll
  for (int c = 0; c < 7; ++c)
#pragma unroll
    for (int r = 0; r < 4; ++r)
      CP[(size_t)(16 * c + quad * 4 + r) * DD + k0 + l15] = acc[c][r];
}

// ---------------- mus update + musq (+ bf16 mus for gemm1) ----------------
__global__ __launch_bounds__(256) void k_musup(const float* __restrict__ musR, const float* __restrict__ SL,
                                               const float* __restrict__ CP, float* __restrict__ musW,
                                               float* __restrict__ musq, short* __restrict__ musb) {
  int w = blockIdx.x, tid = threadIdx.x;
  __shared__ float red[256];
  float q = 0.f;
  for (int k = tid; k < DD; k += 256) {
    size_t o = (size_t)w * DD + k;
    float emus = (SL[o] + CP[o]) / 20.0f;   // p.sum(0) == 5 + 15 exactly
    float m = musR[o];
    float v = m + 0.2f * (emus - m);
    musW[o] = v;
    musb[o] = f2bs(v);
    q += v * v;
  }
  red[tid] = q; __syncthreads();
  for (int o = 128; o > 0; o >>= 1) { if (tid < o) red[tid] += red[tid + o]; __syncthreads(); }
  if (tid == 0) musq[w] = red[0];
}

// ---------------- final logP + acc (P reconstructed from hi+lo) ----------------
__global__ __launch_bounds__(128) void k_final(const short* __restrict__ PTH, const short* __restrict__ PTL,
                                               const int* __restrict__ labels, float* __restrict__ out,
                                               unsigned* __restrict__ ctr) {
  int u = blockIdx.x, tid = threadIdx.x;
  __shared__ float vals[WAY];
  if (tid < WAY) {
    float v = bs2f(PTH[(size_t)tid * PTS + u]) + bs2f(PTL[(size_t)tid * PTS + u]);
    vals[tid] = v;
    out[(size_t)u * WAY + tid] = logf(v + 1e-5f);
  }
  __syncthreads();
  if (tid == 0) {
    int am = 0; float bv = vals[0];
    for (int j = 1; j < WAY; ++j) { if (vals[j] > bv) { bv = vals[j]; am = j; } }
    if (am == labels[N_L + u]) atomicAdd(ctr, 1u);
  }
}

__global__ void k_acc(const unsigned* __restrict__ ctr, float* __restrict__ out) {
  if (threadIdx.x == 0) out[N_U * WAY] = (float)(*ctr) / 1500.0f;
}

// ---------------- host ----------------
extern "C" void kernel_launch(void* const* d_in, const int* in_sizes, int n_in,
                              void* d_out, int out_size, void* d_ws, size_t ws_size,
                              hipStream_t stream) {
  const float* X = (const float*)d_in[0];
  const int* labels = (const int*)d_in[1];
  float* out = (float*)d_out;
  float* ws = (float*)d_ws;

  float* Z     = ws + OFF_Z;
  short* Zb    = (short*)(ws + OFF_Z);       // overlays labeled Z rows (dead after musinit)
  float* meanL = ws + OFF_MEANL;
  float* meanU = ws + OFF_MEANU;
  float* binit = ws + OFF_MEANL;             // meanL dead after k_center
  float* SL    = ws + OFF_SL;
  float* musA  = ws + OFF_MUSA;
  float* musB  = ws + OFF_MUSB;
  float* musq  = ws + OFF_MUSQ;
  short* musb16 = (short*)(ws + OFF_MUSB16);
  short* PTH   = (short*)(ws + OFF_PTH);
  short* PTL   = (short*)(ws + OFF_PTL);
  float* Kmat  = ws + OFF_KMAT;
  float* cols  = ws + OFF_COLS;
  float* misc_f = ws + OFF_MISC;
  unsigned* misc_u = (unsigned*)(ws + OFF_MISC);
  short* ZuT   = (short*)(ws + OFF_ZUT);
  float* D2PT  = ws + OFF_D2P;
  float* CP    = ws + OFF_D2P;               // overlaid: disjoint lifetimes within an epoch

  k_pow_norm<<<N_TOT, 256, 0, stream>>>(X, Z, meanL, misc_u);
  k_colmeans<<<dim3(16, 25), 256, 0, stream>>>(Z, meanL, meanU);
  k_center<<<N_TOT, 256, 0, stream>>>(Z, meanL, meanU);
  k_musinit<<<WAY, 256, 0, stream>>>(Z, SL, musA, musq, musb16, binit);
  k_zt<<<dim3(128, 48), 256, 0, stream>>>(Z, ZuT);
  k_zb<<<3072, 256, 0, stream>>>(Z, Zb);     // after k_zt (k_zt reads fp32 Z; Zb overlays Z[0:500])

  float* musR = musA;
  float* musW = musB;
  for (int e = 0; e < 20; ++e) {
    k_gemm1<<<dim3(24, G1_SPLIT), 256, 0, stream>>>(Zb, musb16, D2PT, cols, misc_u);
    k_expK<<<dim3(6, WAY), 256, 0, stream>>>(D2PT, musq, Kmat);
    k_sink<<<SINK_BLOCKS, 256, 0, stream>>>(Kmat, PTH, PTL, cols, binit, misc_u, misc_f);
    k_gemm2<<<256, 64, 0, stream>>>(PTH, PTL, ZuT, CP);
    k_musup<<<WAY, 256, 0, stream>>>(musR, SL, CP, musW, musq, musb16);
    float* tmp = musR; musR = musW; musW = tmp;
  }
  k_gemm1<<<dim3(24, G1_SPLIT), 256, 0, stream>>>(Zb, musb16, D2PT, cols, misc_u);
  k_expK<<<dim3(6, WAY), 256, 0, stream>>>(D2PT, musq, Kmat);
  k_sink<<<SINK_BLOCKS, 256, 0, stream>>>(Kmat, PTH, PTL, cols, binit, misc_u, misc_f);
  k_final<<<N_U, 128, 0, stream>>>(PTH, PTL, labels, out, misc_u + 6);
  k_acc<<<1, 64, 0, stream>>>(misc_u + 6, out);
}